// Round 5
// baseline (527.786 us; speedup 1.0000x reference)
//
#include <hip/hip_runtime.h>
#include <hip/hip_cooperative_groups.h>

namespace cg = cooperative_groups;

namespace {

constexpr int B = 128, N = 2048, E = 32768;
constexpr int LOG2N = 11, LOG2E = 15;
constexpr int QE = E / 4;          // edges per quarter block = 8192
constexpr int LOG2QE = 13;

// ws layout (bytes)
constexpr size_t OFF_H0 = 0;                     // B*N float4 = 4 MB
constexpr size_t OFF_H1 = 4u * 1024 * 1024;      // B*N float4 = 4 MB
constexpr size_t OFF_S8 = 8u * 1024 * 1024;      // B*4 quarters * QE int2 = 32 MB
constexpr size_t OFF_RP = 40u * 1024 * 1024;     // B*4*(N+1) int ~ 4.2 MB

struct Params {
  const float4* x;
  const int*    edge_index;
  const float*  edge_time;
  const float*  timestamp;
  const int*    src_index;
  const int*    dst_index;
  const float*  tw;
  const float*  tb;
  const float*  Wq;
  const float*  Wk;
  const float*  Wv;
  const float*  Wo;
  const float*  bo;
  const float*  W_lin;
  const float*  b_lin;
  float4* h0;
  float4* h1;
  int2*   sorted8;
  int*    row_ptr;
  float*  out;
};

__device__ __forceinline__ float hw_cos(float s)  { float d; asm("v_cos_f32 %0, %1" : "=v"(d) : "v"(s)); return d; }
__device__ __forceinline__ float hw_exp2(float s) { float d; asm("v_exp_f32 %0, %1" : "=v"(d) : "v"(s)); return d; }

// LDS overlay: sort phase needs 73.8 KB, layer phase 32 KB. One block/CU.
struct SortS { int cnt[N]; int wsum[16]; int2 rec[QE]; };

// R3's layer body, parameterized; cursor geometry (s*/c*) passed in regs
// (computed once after the sort phase, reused by both layers).
__device__ __forceinline__ void layer_phase(
    const Params& P, int b, int n, int t, int l,
    const float4* __restrict__ h_in, float4* __restrict__ h_out, float4* lh,
    int s0, int s1, int s2, int s3, int c0, int c1, int c2, int c3) {
  const float4* hb = h_in + (((size_t)b) << LOG2N);
  lh[t] = hb[t];
  lh[t + 1024] = hb[t + 1024];

  const float* tw = P.tw;
  const float* tb = P.tb;
  const float* Wq = P.Wq + l * 16;
  const float* Wk = P.Wk + l * 32;
  const float* Wv = P.Wv + l * 32;
  const float* Wo = P.Wo + l * 16;
  const float* bo = P.bo + l * 4;

  constexpr float INV2PI = 0.15915494309189535f;
  constexpr float QSCALE = 0.70710678118654752f * 1.4426950408889634f;  // rs2*log2e
  float twf2[4], tbf2[4], wq[16], wkh[16], wkp[16], wvh[16], wvp[16];
#pragma unroll
  for (int j = 0; j < 4; j++) { twf2[j] = tw[j] * INV2PI; tbf2[j] = tb[j] * INV2PI; }
#pragma unroll
  for (int j = 0; j < 16; j++) wq[j] = Wq[j];
#pragma unroll
  for (int j = 0; j < 16; j++) { wkh[j] = Wk[j]; wkp[j] = Wk[16 + j]; }
#pragma unroll
  for (int j = 0; j < 16; j++) { wvh[j] = Wv[j]; wvp[j] = Wv[16 + j]; }
  __syncthreads();

  {
    float4 hn = lh[n];
    float q0 = (hn.x * wq[0] + hn.y * wq[4] + hn.z * wq[8]  + hn.w * wq[12]) * QSCALE;
    float q1 = (hn.x * wq[1] + hn.y * wq[5] + hn.z * wq[9]  + hn.w * wq[13]) * QSCALE;
    float q2 = (hn.x * wq[2] + hn.y * wq[6] + hn.z * wq[10] + hn.w * wq[14]) * QSCALE;
    float q3 = (hn.x * wq[3] + hn.y * wq[7] + hn.z * wq[11] + hn.w * wq[15]) * QSCALE;
#pragma unroll
    for (int i = 0; i < 4; i++) {
      wq[i]      = q0 * wkh[i * 4 + 0] + q1 * wkh[i * 4 + 1];  // wH0
      wq[4 + i]  = q2 * wkh[i * 4 + 2] + q3 * wkh[i * 4 + 3];  // wH1
      wq[8 + i]  = q0 * wkp[i * 4 + 0] + q1 * wkp[i * 4 + 1];  // wA
      wq[12 + i] = q2 * wkp[i * 4 + 2] + q3 * wkp[i * 4 + 3];  // wB
    }
  }

  int stage = 0;
  int total = c0 + c1 + c2 + c3;
  int addr = ((b * 4 + 0) << LOG2QE) + s0, rem = c0;
  int b1 = ((b * 4 + 1) << LOG2QE) + s1;
  int b2 = ((b * 4 + 2) << LOG2QE) + s2;
  int b3 = ((b * 4 + 3) << LOG2QE) + s3;
  while (rem <= 0 && stage < 3) {
    ++stage;
    addr = (stage == 1) ? b1 : (stage == 2) ? b2 : b3;
    rem  = (stage == 1) ? c1 : (stage == 2) ? c2 : c3;
  }

#define ADV() do { ++addr; --rem;                                   \
    while (rem <= 0 && stage < 3) { ++stage;                        \
      addr = (stage == 1) ? b1 : (stage == 2) ? b2 : b3;            \
      rem  = (stage == 1) ? c1 : (stage == 2) ? c2 : c3; } } while (0)

  float s0v = 0.f, s1v = 0.f, a00 = 0.f, a01 = 0.f, a10 = 0.f, a11 = 0.f;

  // depth-4 record pipeline; junk prefetch past segment ends stays inside the
  // sorted8/row_ptr ws region (valid memory) and never reaches accumulators.
  const int2* __restrict__ srt = P.sorted8;
  int2 r0 = srt[addr]; ADV();
  int2 r1 = srt[addr]; ADV();
  int2 r2 = srt[addr]; ADV();
  int2 r3 = srt[addr]; ADV();
  float4 hsN = lh[r0.x & (N - 1)];

  for (int it = 0; it < total; ++it) {
    int2 cur = r0;
    float4 hs = hsN;
    r0 = r1; r1 = r2; r2 = r3;
    r3 = srt[addr]; ADV();
    hsN = lh[r0.x & (N - 1)];

    float dt = __int_as_float(cur.y);
    float ph0 = hw_cos(dt * twf2[0] + tbf2[0]);
    float ph1 = hw_cos(dt * twf2[1] + tbf2[1]);
    float ph2 = hw_cos(dt * twf2[2] + tbf2[2]);
    float ph3 = hw_cos(dt * twf2[3] + tbf2[3]);

    float l0 = hs.x * wq[0] + hs.y * wq[1] + hs.z * wq[2]  + hs.w * wq[3]
             + ph0 * wq[8] + ph1 * wq[9] + ph2 * wq[10] + ph3 * wq[11];
    float l1 = hs.x * wq[4] + hs.y * wq[5] + hs.z * wq[6]  + hs.w * wq[7]
             + ph0 * wq[12] + ph1 * wq[13] + ph2 * wq[14] + ph3 * wq[15];

    float p0 = hw_exp2(l0);
    float p1 = hw_exp2(l1);

    float v0 = hs.x * wvh[0] + hs.y * wvh[4] + hs.z * wvh[8]  + hs.w * wvh[12]
             + ph0 * wvp[0] + ph1 * wvp[4] + ph2 * wvp[8]  + ph3 * wvp[12];
    float v1 = hs.x * wvh[1] + hs.y * wvh[5] + hs.z * wvh[9]  + hs.w * wvh[13]
             + ph0 * wvp[1] + ph1 * wvp[5] + ph2 * wvp[9]  + ph3 * wvp[13];
    float v2 = hs.x * wvh[2] + hs.y * wvh[6] + hs.z * wvh[10] + hs.w * wvh[14]
             + ph0 * wvp[2] + ph1 * wvp[6] + ph2 * wvp[10] + ph3 * wvp[14];
    float v3 = hs.x * wvh[3] + hs.y * wvh[7] + hs.z * wvh[11] + hs.w * wvh[15]
             + ph0 * wvp[3] + ph1 * wvp[7] + ph2 * wvp[11] + ph3 * wvp[15];

    s0v += p0; a00 += p0 * v0; a01 += p0 * v1;
    s1v += p1; a10 += p1 * v2; a11 += p1 * v3;
  }
#undef ADV

  float den0 = (s0v == 0.f) ? 1.f : s0v;
  float den1 = (s1v == 0.f) ? 1.f : s1v;
  float at0 = a00 / den0, at1 = a01 / den0, at2 = a10 / den1, at3 = a11 / den1;

  float wof[16], bof[4];
#pragma unroll
  for (int j = 0; j < 16; j++) wof[j] = Wo[j];
#pragma unroll
  for (int j = 0; j < 4; j++) bof[j] = bo[j];

  float4 hn = lh[n];
  float o0 = bof[0] + at0 * wof[0] + at1 * wof[4] + at2 * wof[8]  + at3 * wof[12];
  float o1 = bof[1] + at0 * wof[1] + at1 * wof[5] + at2 * wof[9]  + at3 * wof[13];
  float o2 = bof[2] + at0 * wof[2] + at1 * wof[6] + at2 * wof[10] + at3 * wof[14];
  float o3 = bof[3] + at0 * wof[3] + at1 * wof[7] + at2 * wof[11] + at3 * wof[15];
  h_out[(((size_t)b) << LOG2N) + n] =
      make_float4(fmaxf(hn.x + o0, 0.f), fmaxf(hn.y + o1, 0.f),
                  fmaxf(hn.z + o2, 0.f), fmaxf(hn.w + o3, 0.f));
}

// One cooperative kernel: sort -> layer1 -> layer2 -> final.
// 256 blocks x 1024 threads, 1 block/CU (co-resident, cooperative launch).
// R9 FIX: __launch_bounds__(1024, 4). R8's build got VGPR_Count=64 (compiler
// chased 8 waves/SIMD) -> the ~90-live-VGPR layer body spilled to scratch ->
// 415 us at 8% VALUBusy. min 4 waves/EU == 16 waves/CU == exactly our one
// cooperative block -> VGPR cap 128, no occupancy loss, no spill.
// Sibling pairing: blocks p and p+8 (same XCD under %8 round-robin) handle
// the same batch -> the CSR read in the layer phases is same-XCD L2-warm
// (per-XCD CSR footprint = 16 batches x 256 KB = 4 MB = L2 size).
__global__ __launch_bounds__(1024, 4) void fused_kernel(Params P) {
  __shared__ __align__(16) char smem[sizeof(SortS)];
  int p = blockIdx.x, t = threadIdx.x;
  int xcd = p & 7, slot = p >> 3;          // 32 slots per XCD
  int b = xcd * 16 + (slot >> 1);          // 16 batches per XCD
  int half = slot & 1;

  // ---------------- phase S: sort quarters {2*half, 2*half+1} ----------------
  {
    SortS& S = *reinterpret_cast<SortS*>(smem);
    float ts = P.timestamp[b];
    for (int qi = 0; qi < 2; ++qi) {
      int q = 2 * half + qi;
      int blk = b * 4 + q;
      S.cnt[t] = 0; S.cnt[t + 1024] = 0;
      __syncthreads();

      const int* src_arr = P.edge_index + (((size_t)(2 * b)) << LOG2E) + q * QE;
      const int* dst_arr = P.edge_index + (((size_t)(2 * b + 1)) << LOG2E) + q * QE;
      const float* et    = P.edge_time + (((size_t)b) << LOG2E) + q * QE;

      // single-pass edge staging into registers (static indices)
      int srcv[8], dstv[8]; float dtv[8];
#pragma unroll
      for (int k = 0; k < 8; ++k) {
        int e = t + k * 1024;
        srcv[k] = src_arr[e];
        dstv[k] = dst_arr[e];
        dtv[k]  = ts - et[e];
      }
#pragma unroll
      for (int k = 0; k < 8; ++k) atomicAdd(&S.cnt[dstv[k]], 1);
      __syncthreads();

      // exclusive scan of 2048 counts: wave shuffle + 16-partial scan
      int i0 = 2 * t, i1 = 2 * t + 1;
      int l0 = S.cnt[i0], l1 = S.cnt[i1];
      int sum = l0 + l1;
      int lane = t & 63, wid = t >> 6;
      int incl = sum;
#pragma unroll
      for (int d = 1; d < 64; d <<= 1) {
        int v = __shfl_up(incl, d, 64);
        if (lane >= d) incl += v;
      }
      if (lane == 63) S.wsum[wid] = incl;
      __syncthreads();
      if (t < 16) {
        int v = S.wsum[t];
        int inc = v;
#pragma unroll
        for (int d = 1; d < 16; d <<= 1) {
          int u = __shfl_up(inc, d, 16);
          if (t >= d) inc += u;
        }
        S.wsum[t] = inc - v;
      }
      __syncthreads();
      int run = S.wsum[wid] + (incl - sum);
      int run2 = run + l0;
      int* rp = P.row_ptr + (size_t)blk * (N + 1);
      rp[i0] = run;
      rp[i1] = run2;
      if (t == 1023) rp[N] = QE;
      S.cnt[i0] = run;
      S.cnt[i1] = run2;
      __syncthreads();

      // scatter into LDS CSR from registers
#pragma unroll
      for (int k = 0; k < 8; ++k) {
        int pos = atomicAdd(&S.cnt[dstv[k]], 1);
        S.rec[pos] = make_int2(srcv[k], __float_as_int(dtv[k]));
      }
      __syncthreads();

      // coalesced stream-out
      const int4* rec4 = (const int4*)S.rec;
      int4* out4 = (int4*)(P.sorted8 + (((size_t)blk) << LOG2QE));
      for (int i = t; i < QE / 2; i += 1024) out4[i] = rec4[i];
      __syncthreads();
    }
  }
  __threadfence();
  cg::this_grid().sync();

  // cursor geometry, computed once, reused by both layers
  int n = half * 1024 + t;
  int s0, s1, s2, s3, c0, c1, c2, c3;
  {
    const int* rp0 = P.row_ptr + (size_t)(b * 4 + 0) * (N + 1);
    const int* rp1 = P.row_ptr + (size_t)(b * 4 + 1) * (N + 1);
    const int* rp2 = P.row_ptr + (size_t)(b * 4 + 2) * (N + 1);
    const int* rp3 = P.row_ptr + (size_t)(b * 4 + 3) * (N + 1);
    s0 = rp0[n]; c0 = rp0[n + 1] - s0;
    s1 = rp1[n]; c1 = rp1[n + 1] - s1;
    s2 = rp2[n]; c2 = rp2[n + 1] - s2;
    s3 = rp3[n]; c3 = rp3[n + 1] - s3;
  }

  float4* lh = reinterpret_cast<float4*>(smem);

  // ---------------- phase L1 ----------------
  layer_phase(P, b, n, t, 0, P.x, P.h1, lh, s0, s1, s2, s3, c0, c1, c2, c3);
  __threadfence();
  cg::this_grid().sync();

  // ---------------- phase L2 ----------------
  layer_phase(P, b, n, t, 1, P.h1, P.h0, lh, s0, s1, s2, s3, c0, c1, c2, c3);
  __threadfence();
  cg::this_grid().sync();

  // ---------------- phase F ----------------
  if (p == 0 && t < B) {
    int bb = t;
    float4 sx = P.h0[(((size_t)bb) << LOG2N) + P.src_index[bb]];
    float4 dx = P.h0[(((size_t)bb) << LOG2N) + P.dst_index[bb]];
    float ts = P.timestamp[bb];
    float f[12];
    f[0] = sx.x; f[1] = sx.y; f[2] = sx.z; f[3] = sx.w;
    f[4] = dx.x; f[5] = dx.y; f[6] = dx.z; f[7] = dx.w;
#pragma unroll
    for (int j = 0; j < 4; j++) f[8 + j] = __cosf(ts * P.tw[j] + P.tb[j]);
#pragma unroll
    for (int c = 0; c < 2; c++) {
      float o = P.b_lin[c];
#pragma unroll
      for (int j = 0; j < 12; j++) o += f[j] * P.W_lin[j * 2 + c];
      P.out[bb * 2 + c] = o;
    }
  }
}

}  // namespace

extern "C" void kernel_launch(void* const* d_in, const int* in_sizes, int n_in,
                              void* d_out, int out_size, void* d_ws, size_t ws_size,
                              hipStream_t stream) {
  (void)in_sizes; (void)n_in; (void)out_size; (void)ws_size;
  char* ws = (char*)d_ws;

  Params hp;
  hp.x          = (const float4*)d_in[0];
  hp.edge_index = (const int*)d_in[1];
  hp.edge_time  = (const float*)d_in[2];
  hp.timestamp  = (const float*)d_in[3];
  hp.src_index  = (const int*)d_in[4];
  hp.dst_index  = (const int*)d_in[5];
  hp.tw         = (const float*)d_in[6];
  hp.tb         = (const float*)d_in[7];
  hp.Wq         = (const float*)d_in[8];
  hp.Wk         = (const float*)d_in[9];
  hp.Wv         = (const float*)d_in[10];
  hp.Wo         = (const float*)d_in[11];
  hp.bo         = (const float*)d_in[12];
  hp.W_lin      = (const float*)d_in[13];
  hp.b_lin      = (const float*)d_in[14];
  hp.h0         = (float4*)(ws + OFF_H0);
  hp.h1         = (float4*)(ws + OFF_H1);
  hp.sorted8    = (int2*)(ws + OFF_S8);
  hp.row_ptr    = (int*)(ws + OFF_RP);
  hp.out        = (float*)d_out;

  void* kargs[] = { (void*)&hp };
  hipLaunchCooperativeKernel((void*)fused_kernel, dim3(2 * B), dim3(1024),
                             kargs, 0, stream);
}

// Round 6
// 268.708 us; speedup vs baseline: 1.9642x; 1.9642x over previous
//
#include <hip/hip_runtime.h>

namespace {

constexpr int B = 128, N = 2048, E = 32768;
constexpr int LOG2N = 11, LOG2E = 15;
constexpr int QE = E / 4;          // records per quarter = 8192
constexpr int LOG2QE = 13;

// ws layout (bytes): total 44.02 MB (previous rounds used 44.2 -> fits)
constexpr size_t OFF_S8 = 0;                          // CSR records: 32 MB
constexpr size_t OFF_P1 = 32u * 1024 * 1024;          // layer1 partials: B*2*6*N*4 = 12 MB
constexpr size_t OFF_O2 = OFF_P1 + 12u * 1024 * 1024; // layer2 node partials: 24 KB

__device__ __forceinline__ float hw_cos(float s)  { float d; asm("v_cos_f32 %0, %1" : "=v"(d) : "v"(s)); return d; }
__device__ __forceinline__ float hw_exp2(float s) { float d; asm("v_exp_f32 %0, %1" : "=v"(d) : "v"(s)); return d; }

// One block per (batch, quarter): LDS counting-sort of records by dst.
// R10: rec packs (src | dst<<16, dt) so edge-parallel consumers know dst;
// row_ptr dropped entirely (nothing reads it anymore).
__global__ __launch_bounds__(1024) void sort_kernel(const int* __restrict__ edge_index,
                                                    const float* __restrict__ edge_time,
                                                    const float* __restrict__ timestamp,
                                                    int2* __restrict__ sorted8) {
  __shared__ int  cnt[N];        // 8 KB: counts -> cursors
  __shared__ int  wsum[16];
  __shared__ int2 rec[QE];       // 64 KB
  int blk = blockIdx.x, b = blk >> 2, q = blk & 3, t = threadIdx.x;

  cnt[t] = 0; cnt[t + 1024] = 0;
  __syncthreads();

  const int* src_arr = edge_index + (((size_t)(2 * b)) << LOG2E) + q * QE;
  const int* dst_arr = edge_index + (((size_t)(2 * b + 1)) << LOG2E) + q * QE;
  const float* et    = edge_time + (((size_t)b) << LOG2E) + q * QE;
  float ts = timestamp[b];

  // single-pass edge staging into registers (static indices)
  int srcv[8], dstv[8]; float dtv[8];
#pragma unroll
  for (int k = 0; k < 8; ++k) {
    int e = t + k * 1024;
    srcv[k] = src_arr[e];
    dstv[k] = dst_arr[e];
    dtv[k]  = ts - et[e];
  }
#pragma unroll
  for (int k = 0; k < 8; ++k) atomicAdd(&cnt[dstv[k]], 1);
  __syncthreads();

  // exclusive scan of 2048 counts: wave shuffle + 16-partial scan
  int i0 = 2 * t, i1 = 2 * t + 1;
  int l0 = cnt[i0], l1 = cnt[i1];
  int sum = l0 + l1;
  int lane = t & 63, wid = t >> 6;
  int incl = sum;
#pragma unroll
  for (int d = 1; d < 64; d <<= 1) {
    int v = __shfl_up(incl, d, 64);
    if (lane >= d) incl += v;
  }
  if (lane == 63) wsum[wid] = incl;
  __syncthreads();
  if (t < 16) {
    int v = wsum[t];
    int inc = v;
#pragma unroll
    for (int d = 1; d < 16; d <<= 1) {
      int u = __shfl_up(inc, d, 16);
      if (t >= d) inc += u;
    }
    wsum[t] = inc - v;
  }
  __syncthreads();
  int run = wsum[wid] + (incl - sum);
  cnt[i0] = run;
  cnt[i1] = run + l0;
  __syncthreads();

  // scatter into LDS CSR from registers, packing dst into the record
#pragma unroll
  for (int k = 0; k < 8; ++k) {
    int pos = atomicAdd(&cnt[dstv[k]], 1);
    rec[pos] = make_int2(srcv[k] | (dstv[k] << 16), __float_as_int(dtv[k]));
  }
  __syncthreads();

  // coalesced stream-out
  const int4* rec4 = (const int4*)rec;
  int4* out4 = (int4*)(sorted8 + (((size_t)blk) << LOG2QE));
  for (int i = t; i < QE / 2; i += 1024) out4[i] = rec4[i];
}

// R10 edge-parallel layer. One block per (batch, half): 16384 consecutive
// sorted records, 16 per thread, fully coalesced loads (no data-dependent
// cursor walk -> no scatter-load stalls). Per 64-record wave window:
// in-register segmented reduction by dst (runs avg 4), only run-tail lanes
// issue 6 LDS float atomics (~1.5 atomics/edge).
// MODE 0: lh = x[b]; writes all-node partials to part1[b][half][6][N].
// MODE 1: lh = h1 reconstructed from x + part1 (merge folded into prologue,
//         h1 never materialized globally); writes only the src/dst nodes'
//         partials to out2 (final kernel needs nothing else).
template <int MODE>
__global__ __launch_bounds__(1024, 4) void layerE_kernel(
    const float4* __restrict__ x, const int2* __restrict__ sorted8,
    const float* __restrict__ part1, float* __restrict__ part1out,
    float* __restrict__ out2,
    const int* __restrict__ src_index, const int* __restrict__ dst_index,
    const float* __restrict__ tw, const float* __restrict__ tb,
    const float* __restrict__ Wq, const float* __restrict__ Wk,
    const float* __restrict__ Wv, const float* __restrict__ WoP,
    const float* __restrict__ boP) {
  __shared__ float4 lh[N];       // 32 KB
  __shared__ float  accS[6 * N]; // 48 KB
  int blk = blockIdx.x, b = blk >> 1, half = blk & 1, t = threadIdx.x;
  int lane = t & 63;

  constexpr float INV2PI = 0.15915494309189535f;
  constexpr float QSCALE = 0.70710678118654752f * 1.4426950408889634f;  // rs2*log2e
  float twf2[4], tbf2[4], wqc[16], wkh[16], wkp[16], wvh[16], wvp[16];
#pragma unroll
  for (int j = 0; j < 4; j++) { twf2[j] = tw[j] * INV2PI; tbf2[j] = tb[j] * INV2PI; }
#pragma unroll
  for (int j = 0; j < 16; j++) wqc[j] = Wq[j] * QSCALE;
#pragma unroll
  for (int j = 0; j < 16; j++) { wkh[j] = Wk[j]; wkp[j] = Wk[16 + j]; }
#pragma unroll
  for (int j = 0; j < 16; j++) { wvh[j] = Wv[j]; wvp[j] = Wv[16 + j]; }

  // ---- prologue: fill lh ----
  if constexpr (MODE == 0) {
    const float4* hb = x + (((size_t)b) << LOG2N);
    lh[t] = hb[t];
    lh[t + 1024] = hb[t + 1024];
  } else {
    const float* p1 = part1 + ((size_t)(b * 2)) * 6 * N;
#pragma unroll
    for (int nn = 0; nn < 2; ++nn) {
      int n = t + nn * 1024;
      float sarr[6];
#pragma unroll
      for (int j = 0; j < 6; j++) sarr[j] = p1[j * N + n] + p1[6 * N + j * N + n];
      float den0 = (sarr[0] == 0.f) ? 1.f : sarr[0];
      float den1 = (sarr[1] == 0.f) ? 1.f : sarr[1];
      float at0 = sarr[2] / den0, at1 = sarr[3] / den0;
      float at2 = sarr[4] / den1, at3 = sarr[5] / den1;
      float4 xb = x[(((size_t)b) << LOG2N) + n];
      float o0 = boP[0] + at0 * WoP[0] + at1 * WoP[4] + at2 * WoP[8]  + at3 * WoP[12];
      float o1 = boP[1] + at0 * WoP[1] + at1 * WoP[5] + at2 * WoP[9]  + at3 * WoP[13];
      float o2 = boP[2] + at0 * WoP[2] + at1 * WoP[6] + at2 * WoP[10] + at3 * WoP[14];
      float o3 = boP[3] + at0 * WoP[3] + at1 * WoP[7] + at2 * WoP[11] + at3 * WoP[15];
      lh[n] = make_float4(fmaxf(xb.x + o0, 0.f), fmaxf(xb.y + o1, 0.f),
                          fmaxf(xb.z + o2, 0.f), fmaxf(xb.w + o3, 0.f));
    }
  }
  // zero accumulators (12288 floats = 3072 float4)
  {
    float4* a4 = (float4*)accS;
    float4 z = make_float4(0.f, 0.f, 0.f, 0.f);
    a4[t] = z; a4[t + 1024] = z; a4[t + 2048] = z;
  }
  __syncthreads();

  // ---- edge loop: 16 windows of 1024 consecutive records ----
  const int2* __restrict__ srt = sorted8 + (((size_t)(b * 4 + half * 2)) << LOG2QE);

#define SEGSCAN(y) do { float u_;                                   \
    u_ = __shfl_up(y, 1, 64);  if (lane - 1  >= hd_i) y += u_;      \
    u_ = __shfl_up(y, 2, 64);  if (lane - 2  >= hd_i) y += u_;      \
    u_ = __shfl_up(y, 4, 64);  if (lane - 4  >= hd_i) y += u_;      \
    u_ = __shfl_up(y, 8, 64);  if (lane - 8  >= hd_i) y += u_;      \
    u_ = __shfl_up(y, 16, 64); if (lane - 16 >= hd_i) y += u_;      \
    u_ = __shfl_up(y, 32, 64); if (lane - 32 >= hd_i) y += u_;      \
  } while (0)

  for (int k = 0; k < 16; ++k) {
    int2 rc = srt[k * 1024 + t];
    int sidx = rc.x & 0xffff;
    int didx = ((unsigned)rc.x) >> 16;
    float dt = __int_as_float(rc.y);
    float4 hs = lh[sidx];
    float4 hd = lh[didx];

    float ph0 = hw_cos(dt * twf2[0] + tbf2[0]);
    float ph1 = hw_cos(dt * twf2[1] + tbf2[1]);
    float ph2 = hw_cos(dt * twf2[2] + tbf2[2]);
    float ph3 = hw_cos(dt * twf2[3] + tbf2[3]);

    float q0 = hd.x * wqc[0] + hd.y * wqc[4] + hd.z * wqc[8]  + hd.w * wqc[12];
    float q1 = hd.x * wqc[1] + hd.y * wqc[5] + hd.z * wqc[9]  + hd.w * wqc[13];
    float q2 = hd.x * wqc[2] + hd.y * wqc[6] + hd.z * wqc[10] + hd.w * wqc[14];
    float q3 = hd.x * wqc[3] + hd.y * wqc[7] + hd.z * wqc[11] + hd.w * wqc[15];

    float k0 = hs.x * wkh[0] + hs.y * wkh[4] + hs.z * wkh[8]  + hs.w * wkh[12]
             + ph0 * wkp[0] + ph1 * wkp[4] + ph2 * wkp[8]  + ph3 * wkp[12];
    float k1 = hs.x * wkh[1] + hs.y * wkh[5] + hs.z * wkh[9]  + hs.w * wkh[13]
             + ph0 * wkp[1] + ph1 * wkp[5] + ph2 * wkp[9]  + ph3 * wkp[13];
    float k2 = hs.x * wkh[2] + hs.y * wkh[6] + hs.z * wkh[10] + hs.w * wkh[14]
             + ph0 * wkp[2] + ph1 * wkp[6] + ph2 * wkp[10] + ph3 * wkp[14];
    float k3 = hs.x * wkh[3] + hs.y * wkh[7] + hs.z * wkh[11] + hs.w * wkh[15]
             + ph0 * wkp[3] + ph1 * wkp[7] + ph2 * wkp[11] + ph3 * wkp[15];

    float p0 = hw_exp2(q0 * k0 + q1 * k1);
    float p1 = hw_exp2(q2 * k2 + q3 * k3);

    float v0 = hs.x * wvh[0] + hs.y * wvh[4] + hs.z * wvh[8]  + hs.w * wvh[12]
             + ph0 * wvp[0] + ph1 * wvp[4] + ph2 * wvp[8]  + ph3 * wvp[12];
    float v1 = hs.x * wvh[1] + hs.y * wvh[5] + hs.z * wvh[9]  + hs.w * wvh[13]
             + ph0 * wvp[1] + ph1 * wvp[5] + ph2 * wvp[9]  + ph3 * wvp[13];
    float v2 = hs.x * wvh[2] + hs.y * wvh[6] + hs.z * wvh[10] + hs.w * wvh[14]
             + ph0 * wvp[2] + ph1 * wvp[6] + ph2 * wvp[10] + ph3 * wvp[14];
    float v3 = hs.x * wvh[3] + hs.y * wvh[7] + hs.z * wvh[11] + hs.w * wvh[15]
             + ph0 * wvp[3] + ph1 * wvp[7] + ph2 * wvp[11] + ph3 * wvp[15];

    float y0 = p0, y1 = p1;
    float y2 = p0 * v0, y3 = p0 * v1, y4 = p1 * v2, y5 = p1 * v3;

    // segment head index within the 64-lane window
    int dprev = __shfl_up(didx, 1, 64);
    int hd_i = (lane == 0 || didx != dprev) ? lane : 0;
#pragma unroll
    for (int d = 1; d < 64; d <<= 1) {
      int u = __shfl_up(hd_i, d, 64);
      if (lane >= d) hd_i = max(hd_i, u);
    }
    SEGSCAN(y0); SEGSCAN(y1); SEGSCAN(y2); SEGSCAN(y3); SEGSCAN(y4); SEGSCAN(y5);

    int dnext = __shfl_down(didx, 1, 64);
    bool tail = (lane == 63) || (didx != dnext);
    if (tail) {
      atomicAdd(&accS[0 * N + didx], y0);
      atomicAdd(&accS[1 * N + didx], y1);
      atomicAdd(&accS[2 * N + didx], y2);
      atomicAdd(&accS[3 * N + didx], y3);
      atomicAdd(&accS[4 * N + didx], y4);
      atomicAdd(&accS[5 * N + didx], y5);
    }
  }
#undef SEGSCAN

  __syncthreads();

  // ---- epilogue ----
  if constexpr (MODE == 0) {
    float* po = part1out + ((size_t)(b * 2 + half)) * 6 * N;
#pragma unroll
    for (int j = 0; j < 6; j++) {
      po[j * N + t] = accS[j * N + t];
      po[j * N + t + 1024] = accS[j * N + t + 1024];
    }
  } else {
    if (t < 12) {
      int slot = t / 6, j = t % 6;
      int node = (slot == 0) ? src_index[b] : dst_index[b];
      out2[(((size_t)(b * 2 + half)) * 2 + slot) * 6 + j] = accS[j * N + node];
    }
  }
}

// Final: reconstruct h1 (x + part1, layer0 Wo/bo) and h2 (h1 + out2, layer1
// Wo/bo) for just the src/dst nodes, then the linear head.
__global__ void final_kernel(const float4* __restrict__ x,
                             const float* __restrict__ part1,
                             const float* __restrict__ out2,
                             const int* __restrict__ src_index, const int* __restrict__ dst_index,
                             const float* __restrict__ timestamp,
                             const float* __restrict__ tw, const float* __restrict__ tb,
                             const float* __restrict__ Wo, const float* __restrict__ bo,
                             const float* __restrict__ W_lin, const float* __restrict__ b_lin,
                             float* __restrict__ out) {
  int b = threadIdx.x;
  if (b >= B) return;
  int nodes[2] = { src_index[b], dst_index[b] };
  float ts = timestamp[b];
  const float* p1 = part1 + ((size_t)(b * 2)) * 6 * N;
  float h2v[2][4];
#pragma unroll
  for (int slot = 0; slot < 2; ++slot) {
    int n = nodes[slot];
    // h1 reconstruction (must match MODE1 prologue numerics)
    float sarr[6];
#pragma unroll
    for (int j = 0; j < 6; j++) sarr[j] = p1[j * N + n] + p1[6 * N + j * N + n];
    float den0 = (sarr[0] == 0.f) ? 1.f : sarr[0];
    float den1 = (sarr[1] == 0.f) ? 1.f : sarr[1];
    float at0 = sarr[2] / den0, at1 = sarr[3] / den0;
    float at2 = sarr[4] / den1, at3 = sarr[5] / den1;
    float4 xb = x[(((size_t)b) << LOG2N) + n];
    float h10 = fmaxf(xb.x + bo[0] + at0 * Wo[0] + at1 * Wo[4] + at2 * Wo[8]  + at3 * Wo[12], 0.f);
    float h11 = fmaxf(xb.y + bo[1] + at0 * Wo[1] + at1 * Wo[5] + at2 * Wo[9]  + at3 * Wo[13], 0.f);
    float h12 = fmaxf(xb.z + bo[2] + at0 * Wo[2] + at1 * Wo[6] + at2 * Wo[10] + at3 * Wo[14], 0.f);
    float h13 = fmaxf(xb.w + bo[3] + at0 * Wo[3] + at1 * Wo[7] + at2 * Wo[11] + at3 * Wo[15], 0.f);
    // layer-2 attn from out2 partials
    float t2[6];
#pragma unroll
    for (int j = 0; j < 6; j++)
      t2[j] = out2[(((size_t)(b * 2 + 0)) * 2 + slot) * 6 + j]
            + out2[(((size_t)(b * 2 + 1)) * 2 + slot) * 6 + j];
    float d20 = (t2[0] == 0.f) ? 1.f : t2[0];
    float d21 = (t2[1] == 0.f) ? 1.f : t2[1];
    float b0 = t2[2] / d20, b1 = t2[3] / d20, b2 = t2[4] / d21, b3 = t2[5] / d21;
    const float* Wo1 = Wo + 16; const float* bo1 = bo + 4;
    h2v[slot][0] = fmaxf(h10 + bo1[0] + b0 * Wo1[0] + b1 * Wo1[4] + b2 * Wo1[8]  + b3 * Wo1[12], 0.f);
    h2v[slot][1] = fmaxf(h11 + bo1[1] + b0 * Wo1[1] + b1 * Wo1[5] + b2 * Wo1[9]  + b3 * Wo1[13], 0.f);
    h2v[slot][2] = fmaxf(h12 + bo1[2] + b0 * Wo1[2] + b1 * Wo1[6] + b2 * Wo1[10] + b3 * Wo1[14], 0.f);
    h2v[slot][3] = fmaxf(h13 + bo1[3] + b0 * Wo1[3] + b1 * Wo1[7] + b2 * Wo1[11] + b3 * Wo1[15], 0.f);
  }
  float f[12];
#pragma unroll
  for (int j = 0; j < 4; j++) { f[j] = h2v[0][j]; f[4 + j] = h2v[1][j]; }
#pragma unroll
  for (int j = 0; j < 4; j++) f[8 + j] = __cosf(ts * tw[j] + tb[j]);
#pragma unroll
  for (int c = 0; c < 2; c++) {
    float o = b_lin[c];
#pragma unroll
    for (int j = 0; j < 12; j++) o += f[j] * W_lin[j * 2 + c];
    out[b * 2 + c] = o;
  }
}

}  // namespace

extern "C" void kernel_launch(void* const* d_in, const int* in_sizes, int n_in,
                              void* d_out, int out_size, void* d_ws, size_t ws_size,
                              hipStream_t stream) {
  (void)in_sizes; (void)n_in; (void)out_size; (void)ws_size;
  const float* x         = (const float*)d_in[0];
  const int*   edge_idx  = (const int*)d_in[1];
  const float* edge_time = (const float*)d_in[2];
  const float* timestamp = (const float*)d_in[3];
  const int*   src_index = (const int*)d_in[4];
  const int*   dst_index = (const int*)d_in[5];
  const float* time_w    = (const float*)d_in[6];
  const float* time_b    = (const float*)d_in[7];
  const float* Wq        = (const float*)d_in[8];
  const float* Wk        = (const float*)d_in[9];
  const float* Wv        = (const float*)d_in[10];
  const float* Wo        = (const float*)d_in[11];
  const float* bo        = (const float*)d_in[12];
  const float* W_lin     = (const float*)d_in[13];
  const float* b_lin     = (const float*)d_in[14];

  char* ws = (char*)d_ws;
  int2*  sorted8 = (int2*)(ws + OFF_S8);
  float* part1   = (float*)(ws + OFF_P1);
  float* out2    = (float*)(ws + OFF_O2);

  sort_kernel<<<4 * B, 1024, 0, stream>>>(edge_idx, edge_time, timestamp, sorted8);

  layerE_kernel<0><<<2 * B, 1024, 0, stream>>>(
      (const float4*)x, sorted8, nullptr, part1, nullptr, src_index, dst_index,
      time_w, time_b, Wq + 0, Wk + 0, Wv + 0, nullptr, nullptr);

  layerE_kernel<1><<<2 * B, 1024, 0, stream>>>(
      (const float4*)x, sorted8, part1, nullptr, out2, src_index, dst_index,
      time_w, time_b, Wq + 16, Wk + 32, Wv + 32, Wo + 0, bo + 0);

  final_kernel<<<1, 128, 0, stream>>>(
      (const float4*)x, part1, out2, src_index, dst_index, timestamp,
      time_w, time_b, Wo, bo, W_lin, b_lin, (float*)d_out);
}